// Round 11
// baseline (1793.209 us; speedup 1.0000x reference)
//
#include <hip/hip_runtime.h>
#include <hip/hip_bf16.h>

#define IN_DIM 256
#define HID    128
#define NSEG   320
#define MAXNORM 0.99999
#define NN     131072
#define NKEY   524288               // key = (src>>15)<<17 | dst   (4 panels)
#define NIOFF  16385                // 4 panels * 4096 dst-ranges (D=32) + 1

typedef short bf16x8 __attribute__((ext_vector_type(8)));
typedef float f32x4  __attribute__((ext_vector_type(4)));

static __device__ __forceinline__ ushort f2b(float f) {
    uint u = __builtin_bit_cast(uint, f);
    uint r = 0x7FFFu + ((u >> 16) & 1u);      // round-to-nearest-even
    return (ushort)((u + r) >> 16);
}
static __device__ __forceinline__ float b2f_lo(uint v) {
    return __builtin_bit_cast(float, v << 16);
}
static __device__ __forceinline__ float b2f_hi(uint v) {
    return __builtin_bit_cast(float, v & 0xFFFF0000u);
}
static __device__ __forceinline__ uint pk(float lo, float hi) {
    return ((uint)f2b(hi) << 16) | (uint)f2b(lo);
}

// ---------------------------------------------------------------------------
// CSR (524288 keys) + segment-rank, folded kernels
// ---------------------------------------------------------------------------
__global__ void count2_k(const int* __restrict__ src, const int* __restrict__ dst,
                         const int* __restrict__ segid, int* __restrict__ counts,
                         int* __restrict__ scnt, int E, int N) {
    int e = blockIdx.x * 256 + threadIdx.x;
    if (e < E) atomicAdd(&counts[((src[e] >> 15) << 17) | dst[e]], 1);
    if (e < N) atomicAdd(&scnt[segid[e]], 1);
}

__global__ void scan_block_k(const int* __restrict__ in, int* __restrict__ out,
                             int* __restrict__ partials) {
    __shared__ int sh[256];
    int tid = threadIdx.x;
    int base = blockIdx.x * 1024 + tid * 4;
    int4 v = *(const int4*)&in[base];
    int s = v.x + v.y + v.z + v.w;
    sh[tid] = s;
    __syncthreads();
#pragma unroll
    for (int off = 1; off < 256; off <<= 1) {
        int t = (tid >= off) ? sh[tid - off] : 0;
        __syncthreads();
        sh[tid] += t;
        __syncthreads();
    }
    int excl = sh[tid] - s;
    int4 o;
    o.x = excl; o.y = excl + v.x; o.z = o.y + v.y; o.w = o.z + v.z;
    *(int4*)&out[base] = o;
    if (tid == 255) partials[blockIdx.x] = sh[255];
}

// block 0: scan 512 scan-partials; block 1: scan 320 segment counts -> sstart
__global__ void scan2_k(int* __restrict__ partials, const int* __restrict__ scnt,
                        int* __restrict__ sstart) {
    __shared__ int sh[512];
    int tid = threadIdx.x;
    if (blockIdx.x == 0) {
        int v = partials[tid];
        sh[tid] = v;
        __syncthreads();
        for (int off = 1; off < 512; off <<= 1) {
            int t = (tid >= off) ? sh[tid - off] : 0;
            __syncthreads();
            sh[tid] += t;
            __syncthreads();
        }
        partials[tid] = sh[tid] - v;
    } else {
        int v = (tid < NSEG) ? scnt[tid] : 0;
        sh[tid] = v;
        __syncthreads();
        for (int off = 1; off < 512; off <<= 1) {
            int t = (tid >= off) ? sh[tid - off] : 0;
            __syncthreads();
            sh[tid] += t;
            __syncthreads();
        }
        if (tid < NSEG) sstart[tid] = sh[tid] - v;
        if (tid == 511) sstart[NSEG] = sh[511];
    }
}

__global__ void add_base_k(int* __restrict__ offsets, const int* __restrict__ partials, int n) {
    int g = blockIdx.x * 256 + threadIdx.x;
    if (g < n) offsets[g] += partials[g >> 10];
}

// packed = src(17b) | (dst&31)<<17 ; also node->segment rank
__global__ void fill2_k(const int* __restrict__ src, const int* __restrict__ dst,
                        const int* __restrict__ segid, const int* __restrict__ offsets,
                        const int* __restrict__ sstart, int* __restrict__ cursor,
                        int* __restrict__ scur, uint* __restrict__ packed,
                        int* __restrict__ rank, int E, int N) {
    int e = blockIdx.x * 256 + threadIdx.x;
    if (e < E) {
        int s = src[e], d = dst[e];
        int key = ((s >> 15) << 17) | d;
        int pos = atomicAdd(&cursor[key], 1);
        packed[offsets[key] + pos] = (uint)s | ((uint)(d & 31) << 17);
    }
    if (e < N) {
        int sg = segid[e];
        rank[e] = sstart[sg] + atomicAdd(&scur[sg], 1);
    }
}

__global__ void extract_ioff_k(const int* __restrict__ offsets, int* __restrict__ ioff, int E) {
    int i = blockIdx.x * 256 + threadIdx.x;
    if (i < NIOFF - 1) ioff[i] = offsets[((i >> 12) << 17) | ((i & 4095) << 5)];
    if (i == NIOFF - 1) ioff[i] = E;
}

// ---------------------------------------------------------------------------
// W pre-transpose+convert
// ---------------------------------------------------------------------------
__global__ void prep_wt_k(const float* __restrict__ w1, const float* __restrict__ w2,
                          ushort* __restrict__ w1t, ushort* __restrict__ w2t) {
    int id = blockIdx.x * 256 + threadIdx.x;
    if (id < 32768) {
        int n = id >> 8, k = id & 255;
        w1t[n * 256 + k] = f2b(w1[k * 128 + n]);
    } else {
        int id2 = id - 32768;
        int n = id2 >> 7, k = id2 & 127;
        w2t[n * 128 + k] = f2b(w2[k * 128 + n]);
    }
}

// ---------------------------------------------------------------------------
// bf16 MFMA GEMM. C split CLo/CHi (cols 0-63 / 64-127). For K=128 the A
// operand is also split (ALo/AHi, 64 cols each, selected by k0).
// ---------------------------------------------------------------------------
template<bool AF32>
__global__ __launch_bounds__(256) void gemm_k(const void* __restrict__ ALo,
                                              const void* __restrict__ AHi,
                                              const ushort* __restrict__ BT,
                                              ushort* __restrict__ CLo,
                                              ushort* __restrict__ CHi, int K) {
    __shared__ __align__(16) char As[16384];   // [128][64] bf16, swizzled
    __shared__ __align__(16) char Bs[16384];
    const int tid = threadIdx.x;
    const int lane = tid & 63;
    const int wid = tid >> 6;
    const int wr = wid >> 1, wc = wid & 1;
    const int row0 = blockIdx.x * 128;
    f32x4 acc[4][4] = {};

    for (int k0 = 0; k0 < K; k0 += 64) {
        if (AF32) {
            const float* A = (const float*)ALo;
#pragma unroll
            for (int it = 0; it < 8; ++it) {
                int id = tid + it * 256;
                int r = id >> 4, c4 = (id & 15) * 4;
                float4 v = *(const float4*)&A[(size_t)(row0 + r) * K + k0 + c4];
                ushort4 h;
                h.x = f2b(v.x); h.y = f2b(v.y); h.z = f2b(v.z); h.w = f2b(v.w);
                *(ushort4*)(As + ((r * 128 + c4 * 2) ^ ((r & 7) << 4))) = h;
            }
        } else {
            const ushort* A = (const ushort*)(k0 == 0 ? ALo : AHi);
#pragma unroll
            for (int it = 0; it < 4; ++it) {
                int id = tid + it * 256;
                int r = id >> 3, c8 = (id & 7) * 8;
                bf16x8 v = *(const bf16x8*)&A[(size_t)(row0 + r) * 64 + c8];
                *(bf16x8*)(As + ((r * 128 + c8 * 2) ^ ((r & 7) << 4))) = v;
            }
        }
#pragma unroll
        for (int it = 0; it < 4; ++it) {
            int id = tid + it * 256;
            int n = id >> 3, c8 = (id & 7) * 8;
            bf16x8 v = *(const bf16x8*)&BT[(size_t)n * K + k0 + c8];
            *(bf16x8*)(Bs + ((n * 128 + c8 * 2) ^ ((n & 7) << 4))) = v;
        }
        __syncthreads();
#pragma unroll
        for (int kc = 0; kc < 2; ++kc) {
            bf16x8 af[4], bfr[4];
            int kb = (kc * 32 + (lane >> 4) * 8) * 2;
#pragma unroll
            for (int i = 0; i < 4; ++i) {
                int r = wr * 64 + i * 16 + (lane & 15);
                af[i] = *(const bf16x8*)(As + ((r * 128 + kb) ^ ((r & 7) << 4)));
                int n = wc * 64 + i * 16 + (lane & 15);
                bfr[i] = *(const bf16x8*)(Bs + ((n * 128 + kb) ^ ((n & 7) << 4)));
            }
#pragma unroll
            for (int i = 0; i < 4; ++i)
#pragma unroll
                for (int j = 0; j < 4; ++j)
                    acc[i][j] = __builtin_amdgcn_mfma_f32_16x16x32_bf16(
                        af[i], bfr[j], acc[i][j], 0, 0, 0);
        }
        __syncthreads();
    }
    ushort* Cb = wc ? CHi : CLo;               // wave-uniform half select
#pragma unroll
    for (int i = 0; i < 4; ++i)
#pragma unroll
        for (int j = 0; j < 4; ++j)
#pragma unroll
            for (int r = 0; r < 4; ++r) {
                int row = row0 + wr * 64 + i * 16 + (lane >> 4) * 4 + r;
                int col = j * 16 + (lane & 15);          // 0..63 within half
                Cb[(size_t)row * 64 + col] = f2b(acc[i][j][r]);
            }
}

// ---------------------------------------------------------------------------
// phaseA: item = (sweep, panel, 32-dst range). panel = blockIdx&3 (XCD-
// pinned -> 4MB panel L2-resident, r9-validated). 2 edges per dword-instr
// (lane halves); register run-fold; race-free flush via LDS atomicAdd;
// bf16 partial rows streamed out nontemporally.
// ---------------------------------------------------------------------------
__global__ __launch_bounds__(64) void phaseA_k(const uint* __restrict__ supLo,
                                               const uint* __restrict__ supHi,
                                               const uint* __restrict__ packed,
                                               const int* __restrict__ ioff,
                                               uint* __restrict__ partial) {
    __shared__ float acc[32][64];              // 8KB
    const int b = blockIdx.x;
    const int sweep = b >> 14;
    const int i14 = b & 16383;
    const int p = i14 & 3;                     // XCD-pinned panel
    const int dr = i14 >> 2;
    const int lane = threadIdx.x;
    const int c = lane & 31;
    const int half = lane >> 5;
    const uint* sup = sweep ? supHi : supLo;
#pragma unroll
    for (int i = lane; i < 2048; i += 64) ((float*)acc)[i] = 0.f;
    __syncthreads();

    const int ii = p * 4096 + dr;
    int a  = __builtin_amdgcn_readfirstlane(ioff[ii]);
    int bn = __builtin_amdgcn_readfirstlane(ioff[ii + 1]);
    float ax = 0.f, ay = 0.f;
    int prev = -1;
    int e = a;
    for (; e + 8 <= bn; e += 8) {
        uint pe[8];
#pragma unroll
        for (int t = 0; t < 8; ++t) pe[t] = packed[e + t];    // uniform loads
        uint v[4];
#pragma unroll
        for (int t = 0; t < 4; ++t) {
            uint mine = half ? pe[2 * t + 1] : pe[2 * t];
            v[t] = sup[(size_t)(mine & 0x1FFFFu) * 32 + c];   // L2-hit 128B row
        }
#pragma unroll
        for (int t = 0; t < 4; ++t) {
            uint mine = half ? pe[2 * t + 1] : pe[2 * t];
            int dl = (int)(mine >> 17);
            if (dl != prev) {
                if (prev >= 0) {
                    atomicAdd(&acc[prev][2 * c], ax);
                    atomicAdd(&acc[prev][2 * c + 1], ay);
                }
                ax = 0.f; ay = 0.f; prev = dl;
            }
            ax += b2f_lo(v[t]); ay += b2f_hi(v[t]);
        }
    }
    for (; e + 2 <= bn; e += 2) {
        uint pe0 = packed[e], pe1 = packed[e + 1];
        uint mine = half ? pe1 : pe0;
        uint v = sup[(size_t)(mine & 0x1FFFFu) * 32 + c];
        int dl = (int)(mine >> 17);
        if (dl != prev) {
            if (prev >= 0) {
                atomicAdd(&acc[prev][2 * c], ax);
                atomicAdd(&acc[prev][2 * c + 1], ay);
            }
            ax = 0.f; ay = 0.f; prev = dl;
        }
        ax += b2f_lo(v); ay += b2f_hi(v);
    }
    if (e < bn && half == 0) {                 // odd tail edge
        uint pe0 = packed[e];
        uint v = sup[(size_t)(pe0 & 0x1FFFFu) * 32 + c];
        int dl = (int)(pe0 >> 17);
        if (dl != prev) {
            if (prev >= 0) {
                atomicAdd(&acc[prev][2 * c], ax);
                atomicAdd(&acc[prev][2 * c + 1], ay);
            }
            ax = 0.f; ay = 0.f; prev = dl;
        }
        ax += b2f_lo(v); ay += b2f_hi(v);
    }
    if (prev >= 0) {
        atomicAdd(&acc[prev][2 * c], ax);
        atomicAdd(&acc[prev][2 * c + 1], ay);
    }
    __syncthreads();

    size_t obase = ((size_t)(sweep * 4 + p) * NN + (size_t)dr * 32) * 32;
#pragma unroll
    for (int it = 0; it < 16; ++it) {
        int i = lane + it * 64;                // 0..1023
        int node = i >> 5, cc = i & 31;
        uint o = pk(acc[node][2 * cc], acc[node][2 * cc + 1]);
        __builtin_nontemporal_store(o, &partial[obase + i]);
    }
}

// ---------------------------------------------------------------------------
// phaseB1: h1 = tanh(sum_p partial + b1), uint4 cached reads, halves out
// ---------------------------------------------------------------------------
__global__ __launch_bounds__(256) void phaseB1_k(const uint* __restrict__ partial,
                                                 const float* __restrict__ bias,
                                                 uint* __restrict__ h1Lo,
                                                 uint* __restrict__ h1Hi) {
    int j = blockIdx.x * 256 + threadIdx.x;    // [0, NN*8)
    int node = j >> 3, c4 = j & 7;
    const size_t NS = (size_t)NN * 32;
#pragma unroll
    for (int s = 0; s < 2; ++s) {
        float f[8] = {};
#pragma unroll
        for (int p = 0; p < 4; ++p) {
            uint4 v = *(const uint4*)&partial[(s * 4 + p) * NS + (size_t)node * 32 + c4 * 4];
            f[0] += b2f_lo(v.x); f[1] += b2f_hi(v.x);
            f[2] += b2f_lo(v.y); f[3] += b2f_hi(v.y);
            f[4] += b2f_lo(v.z); f[5] += b2f_hi(v.z);
            f[6] += b2f_lo(v.w); f[7] += b2f_hi(v.w);
        }
        const float* bb = bias + s * 64 + c4 * 8;
        uint4 o;
        o.x = pk(tanhf(f[0] + bb[0]), tanhf(f[1] + bb[1]));
        o.y = pk(tanhf(f[2] + bb[2]), tanhf(f[3] + bb[3]));
        o.z = pk(tanhf(f[4] + bb[4]), tanhf(f[5] + bb[5]));
        o.w = pk(tanhf(f[6] + bb[6]), tanhf(f[7] + bb[7]));
        uint* dsb = s ? h1Hi : h1Lo;
        *(uint4*)&dsb[(size_t)node * 32 + c4 * 4] = o;
    }
}

// ---------------------------------------------------------------------------
// phaseB2: h2 = tanh(sum+b2); logmap0(proj) scale; write permuted y[rank]
// ---------------------------------------------------------------------------
__global__ __launch_bounds__(256) void phaseB2_k(const uint* __restrict__ partial,
                                                 const float* __restrict__ bias,
                                                 const int* __restrict__ rank,
                                                 uint* __restrict__ y) {
    int node = (blockIdx.x << 2) | (threadIdx.x >> 6);
    int lane = threadIdx.x & 63;
    int s = lane >> 5, c = lane & 31;
    const size_t NS = (size_t)NN * 32;
    float sx = 0.f, sy = 0.f;
#pragma unroll
    for (int p = 0; p < 4; ++p) {
        uint v = partial[(s * 4 + p) * NS + (size_t)node * 32 + c];
        sx += b2f_lo(v); sy += b2f_hi(v);
    }
    float2 bv = *(const float2*)&bias[s * 64 + 2 * c];
    float hx = tanhf(sx + bv.x), hy = tanhf(sy + bv.y);
    float ss = hx * hx + hy * hy;
#pragma unroll
    for (int o = 32; o > 0; o >>= 1) ss += __shfl_xor(ss, o);
    double rr = sqrt((double)fmaxf(ss, 1e-15f));
    double m = fmin(rr, MAXNORM);
    float f = (float)(atanh(m) / rr);          // logmap0(proj(h)) scale
    y[(size_t)rank[node] * 64 + lane] = pk(hx * f, hy * f);
}

// ---------------------------------------------------------------------------
// Pool: contiguous segment mean over y rows + expmap0/proj. No atomics.
// ---------------------------------------------------------------------------
__global__ __launch_bounds__(256) void pool_k(const uint* __restrict__ y,
                                              const int* __restrict__ sstart,
                                              float* __restrict__ out) {
    __shared__ float red[4][128];
    int s = blockIdx.x;
    int wid = threadIdx.x >> 6, lane = threadIdx.x & 63;
    int a = sstart[s], b = sstart[s + 1];
    float sx = 0.f, sy = 0.f;
    for (int r = a + wid; r < b; r += 4) {
        uint v = y[(size_t)r * 64 + lane];
        sx += b2f_lo(v); sy += b2f_hi(v);
    }
    red[wid][2 * lane] = sx;
    red[wid][2 * lane + 1] = sy;
    __syncthreads();
    if (wid == 0) {
        sx = red[0][2 * lane] + red[1][2 * lane] + red[2][2 * lane] + red[3][2 * lane];
        sy = red[0][2 * lane + 1] + red[1][2 * lane + 1]
           + red[2][2 * lane + 1] + red[3][2 * lane + 1];
        float cnt = fmaxf((float)(b - a), 1.0f);
        float ux = sx / cnt, uy = sy / cnt;
        float ss = ux * ux + uy * uy;
#pragma unroll
        for (int o = 32; o > 0; o >>= 1) ss += __shfl_xor(ss, o);
        double r = sqrt((double)fmaxf(ss, 1e-15f));
        double t = tanh(r);
        double fac = t / r;
        if (t > MAXNORM) fac = MAXNORM / r;
        float f = (float)fac;
        out[s * 128 + 2 * lane] = ux * f;
        out[s * 128 + 2 * lane + 1] = uy * f;
    }
}

// ---------------------------------------------------------------------------
extern "C" void kernel_launch(void* const* d_in, const int* in_sizes, int n_in,
                              void* d_out, int out_size, void* d_ws, size_t ws_size,
                              hipStream_t stream) {
    const float* x   = (const float*)d_in[0];
    const int* src   = (const int*)d_in[1];
    const int* dst   = (const int*)d_in[2];
    const int* segid = (const int*)d_in[3];
    const float* W1  = (const float*)d_in[4];
    const float* b1  = (const float*)d_in[5];
    const float* W2  = (const float*)d_in[6];
    const float* b2  = (const float*)d_in[7];
    float* out       = (float*)d_out;

    const int N = in_sizes[3];          // 131072
    const int E = in_sizes[1];          // 2097152

    char* ws = (char*)d_ws;
    uint*   partial = (uint*)(ws);                       // [8][N][32]u = 128MB
    ushort* supLo   = (ushort*)(ws + 134217728);         // 16MB [N][64] bf16
    ushort* supHi   = (ushort*)(ws + 150994944);         // 16MB
    ushort* h1Lo    = (ushort*)(ws + 167772160);         // 16MB
    ushort* h1Hi    = (ushort*)(ws + 184549376);         // 16MB
    uint*   y32     = (uint*)(ws + 201326592);           // 32MB [N][64]u
    uint*   packed  = (uint*)(ws + 234881024);           // 8MB
    int* counts     = (int*)(ws + 243269632);            // 2MB, memset region start
    int* cursor     = (int*)(ws + 245366784);            // 2MB
    int* scnt       = (int*)(ws + 247463936);            // 1536B
    int* scur       = (int*)(ws + 247465472);            // 1536B, memset region end
    int* offsets    = (int*)(ws + 247467008);            // 2MB
    int* spart      = (int*)(ws + 249564160);            // 2KB (512 ints)
    int* ioff       = (int*)(ws + 249566208);            // 64KB+
    int* sstart     = (int*)(ws + 249632768);            // 1284B
    int* rank       = (int*)(ws + 249634816);            // 512KB
    ushort* w1t     = (ushort*)(ws + 250159104);         // 64KB
    ushort* w2t     = (ushort*)(ws + 250224640);         // 32KB

    // one memset covers counts|cursor|scnt|scur (contiguous)
    hipMemsetAsync(counts, 0, 4197376, stream);

    const int eblocks = (E + 255) / 256;

    prep_wt_k<<<192, 256, 0, stream>>>(W1, W2, w1t, w2t);

    count2_k<<<eblocks, 256, 0, stream>>>(src, dst, segid, counts, scnt, E, N);
    scan_block_k<<<NKEY / 1024, 256, 0, stream>>>(counts, offsets, spart);
    scan2_k<<<2, 512, 0, stream>>>(spart, scnt, sstart);
    add_base_k<<<NKEY / 256, 256, 0, stream>>>(offsets, spart, NKEY);
    fill2_k<<<eblocks, 256, 0, stream>>>(src, dst, segid, offsets, sstart,
                                         cursor, scur, packed, rank, E, N);
    extract_ioff_k<<<(NIOFF + 255) / 256, 256, 0, stream>>>(offsets, ioff, E);

    // layer 1
    gemm_k<true><<<N / 128, 256, 0, stream>>>(x, nullptr, w1t, supLo, supHi, IN_DIM);
    phaseA_k<<<32768, 64, 0, stream>>>((const uint*)supLo, (const uint*)supHi,
                                       packed, ioff, partial);
    phaseB1_k<<<(N * 8) / 256, 256, 0, stream>>>(partial, b1, (uint*)h1Lo, (uint*)h1Hi);

    // layer 2
    gemm_k<false><<<N / 128, 256, 0, stream>>>(h1Lo, h1Hi, w2t, supLo, supHi, HID);
    phaseA_k<<<32768, 64, 0, stream>>>((const uint*)supLo, (const uint*)supHi,
                                       packed, ioff, partial);
    phaseB2_k<<<N / 4, 256, 0, stream>>>(partial, b2, rank, y32);

    pool_k<<<NSEG, 256, 0, stream>>>(y32, sstart, out);
}